// Round 1
// 6212.959 us; speedup vs baseline: 1.4393x; 1.4393x over previous
//
#include <hip/hip_runtime.h>
#include <hip/hip_cooperative_groups.h>

#define B_  256
#define T_  128
#define I_  512
#define E_  1024
#define F_  2048
#define O_  22
#define L_  6
#define EPS_ 1e-5f

typedef __attribute__((ext_vector_type(8))) short short8;
typedef __attribute__((ext_vector_type(4))) float floatx4;

static __device__ __forceinline__ unsigned short f2bf(float f) {
    unsigned int u = __builtin_bit_cast(unsigned int, f);
    u += 0x7fffu + ((u >> 16) & 1u);          // round-to-nearest-even
    return (unsigned short)(u >> 16);
}
static __device__ __forceinline__ float sigf(float x) {
    return 1.f / (1.f + __expf(-x));
}
static __device__ __forceinline__ float tanhf_(float x) {
    return 2.f / (1.f + __expf(-2.f * x)) - 1.f;
}

// ---------------------------------------------------------------- prep ----
// x fp32 -> bf16, w_ih fp32 -> bf16, zero h_buf[0], zero barrier counters
__global__ void prep_kernel(const float* __restrict__ x,
                            const float* __restrict__ w_ih,
                            unsigned short* __restrict__ x_bf,
                            unsigned short* __restrict__ wih_bf,
                            unsigned short* __restrict__ h0,
                            unsigned int* __restrict__ cnt) {
    const long long NX4 = (long long)B_ * T_ * I_ / 4;   // 4,194,304
    const long long NW4 = (long long)4 * E_ * I_ / 4;    //   524,288
    const long long NH16 = (long long)B_ * E_ / 8;       //    32,768 (uint4 = 8 bf16)
    const long long NC4 = (long long)T_ * 4 * 32 / 4;    //     4,096 (uint4 = 4 uints)
    const long long total = NX4 + NW4 + NH16 + NC4;
    const long long stride = (long long)gridDim.x * blockDim.x;
    for (long long i = (long long)blockIdx.x * blockDim.x + threadIdx.x; i < total; i += stride) {
        if (i < NX4) {
            float4 v = ((const float4*)x)[i];
            ushort4 o;
            o.x = f2bf(v.x); o.y = f2bf(v.y); o.z = f2bf(v.z); o.w = f2bf(v.w);
            ((ushort4*)x_bf)[i] = o;
        } else if (i < NX4 + NW4) {
            long long j = i - NX4;
            float4 v = ((const float4*)w_ih)[j];
            ushort4 o;
            o.x = f2bf(v.x); o.y = f2bf(v.y); o.z = f2bf(v.z); o.w = f2bf(v.w);
            ((ushort4*)wih_bf)[j] = o;
        } else if (i < NX4 + NW4 + NH16) {
            long long j = i - NX4 - NW4;
            ((uint4*)h0)[j] = make_uint4(0u, 0u, 0u, 0u);
        } else {
            long long j = i - NX4 - NW4 - NH16;
            ((uint4*)cnt)[j] = make_uint4(0u, 0u, 0u, 0u);
        }
    }
}

// ---------------------------------------------------------------- LSTM ----
// Persistent kernel. 256 blocks x 256 threads (1 block/CU via 132KB LDS).
// Block (r = bid&3, e4 = bid>>2): rows r*64..+64, gate cols {g*1024 + e4*16 + 0..15}.
// w_hh 64-col slice lives in LDS (bf16) for all 128 steps. c stays in registers.
//
// Sync: per-step, per-row-group barrier. Block (r,e4) only depends on the 64
// blocks sharing r (they produce h rows r*64..+64). One atomicAdd (agent scope)
// per block per step + tight relaxed spin — replaces cg::grid_group::sync(),
// whose conservative 2-phase implementation dominated the runtime (45.6 us/step
// at MfmaUtil 2.8%). The x-phase (no h dependency) is issued BEFORE the wait,
// hiding barrier skew behind independent MFMA work.
#define WHH_STRIDE 1032   // 1024 + 8 pad (shorts)

__global__ void __launch_bounds__(256, 1)
lstm_kernel(const unsigned short* __restrict__ x_bf,
            const unsigned short* __restrict__ wih_bf,
            const float* __restrict__ w_hh,
            const float* __restrict__ b_ih,
            const float* __restrict__ b_hh,
            unsigned short* __restrict__ h_buf,   // 2 * 256*1024 bf16 (ping-pong)
            float* __restrict__ h_f32,            // final h, fp32
            unsigned int* cnt)                    // [T][4] arrive counters, 128B apart
{
    extern __shared__ unsigned short lds_whh[];   // [64][WHH_STRIDE]
    const int tid  = threadIdx.x;
    const int bid  = blockIdx.x;
    const int r    = bid & 3;
    const int e4   = bid >> 2;
    const int wid  = tid >> 6;
    const int lane = tid & 63;
    const int quad = lane >> 4;
    const int ln   = lane & 15;

    // one-time: w_hh slice -> LDS bf16
    for (int idx4 = tid; idx4 < 64 * 1024 / 4; idx4 += 256) {
        int elem = idx4 * 4;
        int c = elem >> 10;          // local col 0..63
        int k = elem & 1023;
        int cg = (c >> 4) * E_ + e4 * 16 + (c & 15);   // gate*1024 + e
        float4 w = *(const float4*)(w_hh + (size_t)cg * E_ + k);
        unsigned int u0 = (unsigned int)f2bf(w.x) | ((unsigned int)f2bf(w.y) << 16);
        unsigned int u1 = (unsigned int)f2bf(w.z) | ((unsigned int)f2bf(w.w) << 16);
        *(uint2*)(lds_whh + (size_t)c * WHH_STRIDE + k) = make_uint2(u0, u1);
    }
    float bias4[4];
#pragma unroll
    for (int ct = 0; ct < 4; ++ct) {
        int cg = ct * E_ + e4 * 16 + ln;
        bias4[ct] = b_ih[cg] + b_hh[cg];
    }
    __syncthreads();

    const int rowA = r * 64 + wid * 16 + ln;   // A-operand row (batch index)
    const int colE = e4 * 16 + ln;             // e-column for C/D & cell state
    float c_reg[4] = {0.f, 0.f, 0.f, 0.f};

    for (int t = 0; t < T_; ++t) {
        const unsigned short* hsrc = h_buf + (size_t)(t & 1) * B_ * E_;
        unsigned short*       hdst = h_buf + (size_t)((t & 1) ^ 1) * B_ * E_;

        floatx4 acc[4];
#pragma unroll
        for (int ct = 0; ct < 4; ++ct)
            acc[ct] = (floatx4){bias4[ct], bias4[ct], bias4[ct], bias4[ct]};

        // ---- x phase: K = 512 (w_ih streamed from L1/L2). No h dependency:
        // runs BEFORE the barrier wait, overlapping other blocks' step t-1 tail.
        const unsigned short* xrow = x_bf + ((size_t)rowA * T_ + t) * I_ + quad * 8;
#pragma unroll 4
        for (int k0 = 0; k0 < I_; k0 += 32) {
            short8 a = *(const short8*)(xrow + k0);
#pragma unroll
            for (int ct = 0; ct < 4; ++ct) {
                int cgl = ct * E_ + e4 * 16 + ln;
                short8 b = *(const short8*)(wih_bf + (size_t)cgl * I_ + k0 + quad * 8);
                acc[ct] = __builtin_amdgcn_mfma_f32_16x16x32_bf16(a, b, acc[ct], 0, 0, 0);
            }
        }

        // ---- wait: all 64 blocks of row-group r finished writing h_{t-1} ----
        if (t) {
            if (tid == 0) {
                unsigned int* cp = cnt + ((size_t)(t - 1) * 4 + r) * 32;
                while (__hip_atomic_load(cp, __ATOMIC_RELAXED, __HIP_MEMORY_SCOPE_AGENT) < 64u)
                    __builtin_amdgcn_s_sleep(1);
                // acquire: invalidate CU L1 (holds stale ping-pong lines from
                // step t-2) and remote L2 lines written on other XCDs.
                __builtin_amdgcn_fence(__ATOMIC_ACQUIRE, "agent");
            }
            __syncthreads();
        }

        // ---- h phase: K = 1024 (w_hh from LDS) ----
        const unsigned short* hrow = hsrc + (size_t)rowA * E_ + quad * 8;
#pragma unroll 4
        for (int k0 = 0; k0 < E_; k0 += 32) {
            short8 a = *(const short8*)(hrow + k0);
#pragma unroll
            for (int ct = 0; ct < 4; ++ct) {
                short8 b = *(const short8*)(lds_whh + (size_t)(ct * 16 + ln) * WHH_STRIDE + k0 + quad * 8);
                acc[ct] = __builtin_amdgcn_mfma_f32_16x16x32_bf16(a, b, acc[ct], 0, 0, 0);
            }
        }
        // ---- elementwise cell update (gates i,f,g,o are lane-aligned) ----
#pragma unroll
        for (int i = 0; i < 4; ++i) {
            float ig = sigf(acc[0][i]);
            float fg = sigf(acc[1][i]);
            float gg = tanhf_(acc[2][i]);
            float og = sigf(acc[3][i]);
            float c = fg * c_reg[i] + ig * gg;
            c_reg[i] = c;
            float h = og * tanhf_(c);
            int row = r * 64 + wid * 16 + quad * 4 + i;   // C/D row = quad*4+reg
            hdst[(size_t)row * E_ + colE] = f2bf(h);
            if (t == T_ - 1) h_f32[(size_t)row * E_ + colE] = h;
        }

        // ---- arrive: publish h_t for row-group r ----
        if (t != T_ - 1) {
            __syncthreads();   // drains vmcnt(0) for all 4 waves' h stores
            if (tid == 0) {
                // release: write back XCD L2 so other XCDs observe h_t
                __builtin_amdgcn_fence(__ATOMIC_RELEASE, "agent");
                __hip_atomic_fetch_add(cnt + ((size_t)t * 4 + r) * 32, 1u,
                                       __ATOMIC_RELAXED, __HIP_MEMORY_SCOPE_AGENT);
            }
        }
        // t == T_-1: kernel end is an implicit device-scope release; h_f32 is
        // consumed by later kernels via stream ordering.
    }
}

// ------------------------------------------------------------- tf_gemm ----
// out[256,N] = [relu]( LN?(A)[256,K] @ W[N,K]^T + bias ) + LN?(res)
// tile 32x32, 4 waves of (mr,nc) 16x16 MFMA tiles. At most ONE of lnA/lnR used.
__global__ void __launch_bounds__(256)
tf_gemm(const float* __restrict__ A, int K,
        const float* __restrict__ lnA_g, const float* __restrict__ lnA_b,
        const float* __restrict__ W, const float* __restrict__ bias, int N,
        const float* __restrict__ res, const float* __restrict__ lnR_g, const float* __restrict__ lnR_b,
        float* __restrict__ out, int do_relu)
{
    __shared__ float s_mean[32], s_rstd[32];
    __shared__ float s_red[2][32][8];
    const int tid = threadIdx.x;
    const int bx = blockIdx.x;
    const int by = blockIdx.y;
    const int rowbase = by * 32;

    const float* stat_src = lnA_g ? A : (lnR_g ? res : nullptr);
    const int statK = lnA_g ? K : E_;
    if (stat_src) {
        int row_l = tid >> 3, seg = tid & 7;
        const float* rp = stat_src + (size_t)(rowbase + row_l) * statK;
        int chunk = statK >> 3;
        float s = 0.f, q = 0.f;
        for (int k = seg * chunk; k < seg * chunk + chunk; k += 4) {
            float4 v = *(const float4*)(rp + k);
            s += v.x + v.y + v.z + v.w;
            q += v.x * v.x + v.y * v.y + v.z * v.z + v.w * v.w;
        }
        s_red[0][row_l][seg] = s;
        s_red[1][row_l][seg] = q;
        __syncthreads();
        if (tid < 32) {
            float ss = 0.f, qq = 0.f;
#pragma unroll
            for (int j = 0; j < 8; ++j) { ss += s_red[0][tid][j]; qq += s_red[1][tid][j]; }
            float m = ss / statK;
            float var = qq / statK - m * m;
            s_mean[tid] = m;
            s_rstd[tid] = rsqrtf(var + EPS_);
        }
        __syncthreads();
    }

    const int wid = tid >> 6, lane = tid & 63, quad = lane >> 4, ln = lane & 15;
    const int mr = wid & 1, nc = wid >> 1;
    const int arow_l = mr * 16 + ln;
    const int col = bx * 32 + nc * 16 + ln;

    floatx4 acc = (floatx4){0.f, 0.f, 0.f, 0.f};
    const float* ap = A + (size_t)(rowbase + arow_l) * K;
    const float* wp = W + (size_t)col * K;
    const bool doLnA = (lnA_g != nullptr);
    float am = 0.f, ars = 1.f;
    if (doLnA) { am = s_mean[arow_l]; ars = s_rstd[arow_l]; }

#pragma unroll 4
    for (int k0 = 0; k0 < K; k0 += 32) {
        int kk = k0 + quad * 8;
        float4 a0 = *(const float4*)(ap + kk);
        float4 a1 = *(const float4*)(ap + kk + 4);
        short8 af, bf;
        if (doLnA) {
            float4 g0 = *(const float4*)(lnA_g + kk);
            float4 g1 = *(const float4*)(lnA_g + kk + 4);
            float4 h0 = *(const float4*)(lnA_b + kk);
            float4 h1 = *(const float4*)(lnA_b + kk + 4);
            af[0] = (short)f2bf((a0.x - am) * ars * g0.x + h0.x);
            af[1] = (short)f2bf((a0.y - am) * ars * g0.y + h0.y);
            af[2] = (short)f2bf((a0.z - am) * ars * g0.z + h0.z);
            af[3] = (short)f2bf((a0.w - am) * ars * g0.w + h0.w);
            af[4] = (short)f2bf((a1.x - am) * ars * g1.x + h1.x);
            af[5] = (short)f2bf((a1.y - am) * ars * g1.y + h1.y);
            af[6] = (short)f2bf((a1.z - am) * ars * g1.z + h1.z);
            af[7] = (short)f2bf((a1.w - am) * ars * g1.w + h1.w);
        } else {
            af[0] = (short)f2bf(a0.x); af[1] = (short)f2bf(a0.y);
            af[2] = (short)f2bf(a0.z); af[3] = (short)f2bf(a0.w);
            af[4] = (short)f2bf(a1.x); af[5] = (short)f2bf(a1.y);
            af[6] = (short)f2bf(a1.z); af[7] = (short)f2bf(a1.w);
        }
        float4 w0 = *(const float4*)(wp + kk);
        float4 w1 = *(const float4*)(wp + kk + 4);
        bf[0] = (short)f2bf(w0.x); bf[1] = (short)f2bf(w0.y);
        bf[2] = (short)f2bf(w0.z); bf[3] = (short)f2bf(w0.w);
        bf[4] = (short)f2bf(w1.x); bf[5] = (short)f2bf(w1.y);
        bf[6] = (short)f2bf(w1.z); bf[7] = (short)f2bf(w1.w);
        acc = __builtin_amdgcn_mfma_f32_16x16x32_bf16(af, bf, acc, 0, 0, 0);
    }

#pragma unroll
    for (int i = 0; i < 4; ++i) {
        int row_l = mr * 16 + quad * 4 + i;
        int row = rowbase + row_l;
        float v = acc[i] + bias[col];
        if (do_relu) v = fmaxf(v, 0.f);
        if (res) {
            float rv = res[(size_t)row * N + col];
            if (lnR_g) rv = (rv - s_mean[row_l]) * s_rstd[row_l] * lnR_g[col] + lnR_b[col];
            v += rv;
        }
        out[(size_t)row * N + col] = v;
    }
}

// ------------------------------------------------- double-LayerNorm ----
// out = LN_{g2,b2}( LN_{g1,b1}(in) ), per row of [256,1024]. 1 wave / row.
__global__ void __launch_bounds__(256)
dual_ln_kernel(const float* __restrict__ in,
               const float* __restrict__ g1, const float* __restrict__ b1,
               const float* __restrict__ g2, const float* __restrict__ b2,
               float* __restrict__ out)
{
    int wid = threadIdx.x >> 6, lane = threadIdx.x & 63;
    int row = blockIdx.x * 4 + wid;
    const float* rp = in + (size_t)row * E_;
    float x[16];
    float s = 0.f;
#pragma unroll
    for (int j = 0; j < 16; j += 4) {
        float4 v = *(const float4*)(rp + lane * 16 + j);
        x[j] = v.x; x[j + 1] = v.y; x[j + 2] = v.z; x[j + 3] = v.w;
        s += v.x + v.y + v.z + v.w;
    }
#pragma unroll
    for (int m = 32; m >= 1; m >>= 1) s += __shfl_xor(s, m, 64);
    float mean = s / E_;
    float q = 0.f;
#pragma unroll
    for (int j = 0; j < 16; ++j) { float d = x[j] - mean; q += d * d; }
#pragma unroll
    for (int m = 32; m >= 1; m >>= 1) q += __shfl_xor(q, m, 64);
    float rs = rsqrtf(q / E_ + EPS_);
    float s2 = 0.f;
#pragma unroll
    for (int j = 0; j < 16; ++j) {
        int k = lane * 16 + j;
        x[j] = (x[j] - mean) * rs * g1[k] + b1[k];
        s2 += x[j];
    }
#pragma unroll
    for (int m = 32; m >= 1; m >>= 1) s2 += __shfl_xor(s2, m, 64);
    float mean2 = s2 / E_;
    float q2 = 0.f;
#pragma unroll
    for (int j = 0; j < 16; ++j) { float d = x[j] - mean2; q2 += d * d; }
#pragma unroll
    for (int m = 32; m >= 1; m >>= 1) q2 += __shfl_xor(q2, m, 64);
    float rs2 = rsqrtf(q2 / E_ + EPS_);
#pragma unroll
    for (int j = 0; j < 16; ++j) {
        int k = lane * 16 + j;
        out[(size_t)row * E_ + k] = (x[j] - mean2) * rs2 * g2[k] + b2[k];
    }
}

// ----------------------------------------------------------- final head ----
// out[row, 0..21] = ( LN_{gn,bn}( LN_{g3,b3}(in[row]) ) ) @ fc_w^T + fc_b
__global__ void __launch_bounds__(64)
head_kernel(const float* __restrict__ in,
            const float* __restrict__ g1, const float* __restrict__ b1,
            const float* __restrict__ g2, const float* __restrict__ b2,
            const float* __restrict__ fc_w, const float* __restrict__ fc_b,
            float* __restrict__ out)
{
    int row = blockIdx.x;
    int lane = threadIdx.x;
    const float* rp = in + (size_t)row * E_;
    float x[16];
    float s = 0.f;
#pragma unroll
    for (int j = 0; j < 16; j += 4) {
        float4 v = *(const float4*)(rp + lane * 16 + j);
        x[j] = v.x; x[j + 1] = v.y; x[j + 2] = v.z; x[j + 3] = v.w;
        s += v.x + v.y + v.z + v.w;
    }
#pragma unroll
    for (int m = 32; m >= 1; m >>= 1) s += __shfl_xor(s, m, 64);
    float mean = s / E_;
    float q = 0.f;
#pragma unroll
    for (int j = 0; j < 16; ++j) { float d = x[j] - mean; q += d * d; }
#pragma unroll
    for (int m = 32; m >= 1; m >>= 1) q += __shfl_xor(q, m, 64);
    float rs = rsqrtf(q / E_ + EPS_);
    float s2 = 0.f;
#pragma unroll
    for (int j = 0; j < 16; ++j) {
        int k = lane * 16 + j;
        x[j] = (x[j] - mean) * rs * g1[k] + b1[k];
        s2 += x[j];
    }
#pragma unroll
    for (int m = 32; m >= 1; m >>= 1) s2 += __shfl_xor(s2, m, 64);
    float mean2 = s2 / E_;
    float q2 = 0.f;
#pragma unroll
    for (int j = 0; j < 16; ++j) { float d = x[j] - mean2; q2 += d * d; }
#pragma unroll
    for (int m = 32; m >= 1; m >>= 1) q2 += __shfl_xor(q2, m, 64);
    float rs2 = rsqrtf(q2 / E_ + EPS_);
#pragma unroll
    for (int j = 0; j < 16; ++j) {
        int k = lane * 16 + j;
        x[j] = (x[j] - mean2) * rs2 * g2[k] + b2[k];
    }
    for (int o = 0; o < O_; ++o) {
        const float* wp = fc_w + (size_t)o * E_ + lane * 16;
        float d = 0.f;
#pragma unroll
        for (int j = 0; j < 16; j += 4) {
            float4 v = *(const float4*)(wp + j);
            d += v.x * x[j] + v.y * x[j + 1] + v.z * x[j + 2] + v.w * x[j + 3];
        }
#pragma unroll
        for (int m = 32; m >= 1; m >>= 1) d += __shfl_xor(d, m, 64);
        if (lane == 0) out[(size_t)row * O_ + o] = d + fc_b[o];
    }
}

// ---------------------------------------------------------------- host ----
extern "C" void kernel_launch(void* const* d_in, const int* in_sizes, int n_in,
                              void* d_out, int out_size, void* d_ws, size_t ws_size,
                              hipStream_t stream) {
    (void)in_sizes; (void)n_in; (void)out_size; (void)ws_size;
    const float* x          = (const float*)d_in[0];
    const float* w_ih       = (const float*)d_in[1];
    const float* w_hh       = (const float*)d_in[2];
    const float* b_ih       = (const float*)d_in[3];
    const float* b_hh       = (const float*)d_in[4];
    const float* enc_attn_w = (const float*)d_in[5];
    const float* enc_attn_b = (const float*)d_in[6];
    const float* enc_out_w  = (const float*)d_in[7];
    const float* enc_out_b  = (const float*)d_in[8];
    const float* enc_ln1_g  = (const float*)d_in[9];
    const float* enc_ln1_b  = (const float*)d_in[10];
    const float* enc_ff1_w  = (const float*)d_in[11];
    const float* enc_ff1_b  = (const float*)d_in[12];
    const float* enc_ff2_w  = (const float*)d_in[13];
    const float* enc_ff2_b  = (const float*)d_in[14];
    const float* enc_ln2_g  = (const float*)d_in[15];
    const float* enc_ln2_b  = (const float*)d_in[16];
    const float* enc_norm_g = (const float*)d_in[17];
    const float* enc_norm_b = (const float*)d_in[18];
    const float* dec_sa_w   = (const float*)d_in[19];
    const float* dec_sa_b   = (const float*)d_in[20];
    const float* dec_sa_out_w = (const float*)d_in[21];
    const float* dec_sa_out_b = (const float*)d_in[22];
    const float* dec_ln1_g  = (const float*)d_in[23];
    const float* dec_ln1_b  = (const float*)d_in[24];
    const float* dec_ca_w   = (const float*)d_in[25];
    const float* dec_ca_b   = (const float*)d_in[26];
    const float* dec_ca_out_w = (const float*)d_in[27];
    const float* dec_ca_out_b = (const float*)d_in[28];
    const float* dec_ln2_g  = (const float*)d_in[29];
    const float* dec_ln2_b  = (const float*)d_in[30];
    const float* dec_ff1_w  = (const float*)d_in[31];
    const float* dec_ff1_b  = (const float*)d_in[32];
    const float* dec_ff2_w  = (const float*)d_in[33];
    const float* dec_ff2_b  = (const float*)d_in[34];
    const float* dec_ln3_g  = (const float*)d_in[35];
    const float* dec_ln3_b  = (const float*)d_in[36];
    const float* dec_norm_g = (const float*)d_in[37];
    const float* dec_norm_b = (const float*)d_in[38];
    const float* fc_w       = (const float*)d_in[39];
    const float* fc_b       = (const float*)d_in[40];
    float* outp = (float*)d_out;

    // ---- workspace layout (~45 MB) ----
    char* wsp = (char*)d_ws;
    unsigned short* x_bf   = (unsigned short*)wsp; wsp += (size_t)B_ * T_ * I_ * 2;
    unsigned short* wih_bf = (unsigned short*)wsp; wsp += (size_t)4 * E_ * I_ * 2;
    unsigned short* h_buf  = (unsigned short*)wsp; wsp += (size_t)2 * B_ * E_ * 2;
    float* h_f32 = (float*)wsp; wsp += (size_t)B_ * E_ * 4;
    float* v_buf = (float*)wsp; wsp += (size_t)B_ * E_ * 4;
    float* uA    = (float*)wsp; wsp += (size_t)B_ * E_ * 4;
    float* uB    = (float*)wsp; wsp += (size_t)B_ * E_ * 4;
    float* t3    = (float*)wsp; wsp += (size_t)B_ * E_ * 4;
    float* memb  = (float*)wsp; wsp += (size_t)B_ * E_ * 4;
    float* F_buf = (float*)wsp; wsp += (size_t)B_ * F_ * 4;
    unsigned int* cnt = (unsigned int*)wsp; wsp += (size_t)T_ * 4 * 32 * 4;  // 64 KB barrier counters

    // ---- phase 1: prep ----
    hipLaunchKernelGGL(prep_kernel, dim3(1024), dim3(256), 0, stream,
                       x, w_ih, x_bf, wih_bf, h_buf, cnt);

    // ---- phase 2: LSTM scan (cooperative launch for co-residency;
    //               sync is the custom per-row-group barrier) ----
    {
        void* args[] = {(void*)&x_bf, (void*)&wih_bf, (void*)&w_hh, (void*)&b_ih,
                        (void*)&b_hh, (void*)&h_buf, (void*)&h_f32, (void*)&cnt};
        hipLaunchCooperativeKernel((void*)lstm_kernel, dim3(256), dim3(256),
                                   args, 64 * WHH_STRIDE * 2, stream);
    }

    // ---- phase 3: transformer ----
    auto gemm = [&](const float* A, int K, const float* g, const float* bA,
                    const float* Wp, const float* bias, int N,
                    const float* res, const float* gR, const float* bR,
                    float* out, int relu_) {
        hipLaunchKernelGGL(tf_gemm, dim3(N / 32, 8), dim3(256), 0, stream,
                           A, K, g, bA, Wp, bias, N, res, gR, bR, out, relu_);
    };
    const float* FN = nullptr;

    // encoder: state (cur, pending LN cg_/cb_)
    const float* cur = h_f32; const float* cg_ = nullptr; const float* cb_ = nullptr;
    for (int l = 0; l < L_; ++l) {
        const float* wv = enc_attn_w + ((size_t)l * 3 * E_ + 2 * E_) * E_;
        const float* bv = enc_attn_b + (size_t)l * 3 * E_ + 2 * E_;
        gemm(cur, E_, cg_, cb_, wv, bv, E_, FN, FN, FN, v_buf, 0);
        gemm(v_buf, E_, FN, FN, enc_out_w + (size_t)l * E_ * E_, enc_out_b + (size_t)l * E_, E_,
             cur, cg_, cb_, uA, 0);
        gemm(uA, E_, enc_ln1_g + l * E_, enc_ln1_b + l * E_,
             enc_ff1_w + (size_t)l * F_ * E_, enc_ff1_b + (size_t)l * F_, F_,
             FN, FN, FN, F_buf, 1);
        gemm(F_buf, F_, FN, FN, enc_ff2_w + (size_t)l * E_ * F_, enc_ff2_b + (size_t)l * E_, E_,
             uA, enc_ln1_g + l * E_, enc_ln1_b + l * E_, uB, 0);
        cur = uB; cg_ = enc_ln2_g + l * E_; cb_ = enc_ln2_b + l * E_;
    }
    hipLaunchKernelGGL(dual_ln_kernel, dim3(64), dim3(256), 0, stream,
                       uB, cg_, cb_, enc_norm_g, enc_norm_b, memb);

    // decoder
    cur = h_f32; cg_ = nullptr; cb_ = nullptr;
    for (int l = 0; l < L_; ++l) {
        const float* wv = dec_sa_w + ((size_t)l * 3 * E_ + 2 * E_) * E_;
        const float* bv = dec_sa_b + (size_t)l * 3 * E_ + 2 * E_;
        gemm(cur, E_, cg_, cb_, wv, bv, E_, FN, FN, FN, v_buf, 0);
        gemm(v_buf, E_, FN, FN, dec_sa_out_w + (size_t)l * E_ * E_, dec_sa_out_b + (size_t)l * E_, E_,
             cur, cg_, cb_, uA, 0);                              // t1 = uA (pending ln1)
        const float* wv2 = dec_ca_w + ((size_t)l * 3 * E_ + 2 * E_) * E_;
        const float* bv2 = dec_ca_b + (size_t)l * 3 * E_ + 2 * E_;
        gemm(memb, E_, FN, FN, wv2, bv2, E_, FN, FN, FN, v_buf, 0);
        gemm(v_buf, E_, FN, FN, dec_ca_out_w + (size_t)l * E_ * E_, dec_ca_out_b + (size_t)l * E_, E_,
             uA, dec_ln1_g + l * E_, dec_ln1_b + l * E_, uB, 0); // t2 = uB (pending ln2)
        gemm(uB, E_, dec_ln2_g + l * E_, dec_ln2_b + l * E_,
             dec_ff1_w + (size_t)l * F_ * E_, dec_ff1_b + (size_t)l * F_, F_,
             FN, FN, FN, F_buf, 1);
        gemm(F_buf, F_, FN, FN, dec_ff2_w + (size_t)l * E_ * F_, dec_ff2_b + (size_t)l * E_, E_,
             uB, dec_ln2_g + l * E_, dec_ln2_b + l * E_, t3, 0); // t3 (pending ln3)
        cur = t3; cg_ = dec_ln3_g + l * E_; cb_ = dec_ln3_b + l * E_;
    }
    hipLaunchKernelGGL(head_kernel, dim3(256), dim3(64), 0, stream,
                       t3, cg_, cb_, dec_norm_g, dec_norm_b, fc_w, fc_b, outp);
}

// Round 2
// 6021.095 us; speedup vs baseline: 1.4851x; 1.0319x over previous
//
#include <hip/hip_runtime.h>
#include <hip/hip_cooperative_groups.h>

#define B_  256
#define T_  128
#define I_  512
#define E_  1024
#define F_  2048
#define O_  22
#define L_  6
#define EPS_ 1e-5f

typedef __attribute__((ext_vector_type(8))) short short8;
typedef __attribute__((ext_vector_type(4))) float floatx4;

static __device__ __forceinline__ unsigned short f2bf(float f) {
    unsigned int u = __builtin_bit_cast(unsigned int, f);
    u += 0x7fffu + ((u >> 16) & 1u);          // round-to-nearest-even
    return (unsigned short)(u >> 16);
}
static __device__ __forceinline__ float sigf(float x) {
    return 1.f / (1.f + __expf(-x));
}
static __device__ __forceinline__ float tanhf_(float x) {
    return 2.f / (1.f + __expf(-2.f * x)) - 1.f;
}

// Store 2B through to the device-coherent point (bypass L1/L2). No fence.
static __device__ __forceinline__ void store_short_coh(unsigned short* p, unsigned int v) {
    asm volatile("global_store_short %0, %1, off sc0 sc1" :: "v"(p), "v"(v) : "memory");
}

// ---------------------------------------------------------------- prep ----
// x fp32 -> bf16, w_ih fp32 -> bf16, zero h_buf[0], zero barrier counters
__global__ void prep_kernel(const float* __restrict__ x,
                            const float* __restrict__ w_ih,
                            unsigned short* __restrict__ x_bf,
                            unsigned short* __restrict__ wih_bf,
                            unsigned short* __restrict__ h0,
                            unsigned int* __restrict__ cnt) {
    const long long NX4 = (long long)B_ * T_ * I_ / 4;   // 4,194,304
    const long long NW4 = (long long)4 * E_ * I_ / 4;    //   524,288
    const long long NH16 = (long long)B_ * E_ / 8;       //    32,768 (uint4 = 8 bf16)
    const long long NC4 = (long long)T_ * 4 * 32 / 4;    //     4,096 (uint4 = 4 uints)
    const long long total = NX4 + NW4 + NH16 + NC4;
    const long long stride = (long long)gridDim.x * blockDim.x;
    for (long long i = (long long)blockIdx.x * blockDim.x + threadIdx.x; i < total; i += stride) {
        if (i < NX4) {
            float4 v = ((const float4*)x)[i];
            ushort4 o;
            o.x = f2bf(v.x); o.y = f2bf(v.y); o.z = f2bf(v.z); o.w = f2bf(v.w);
            ((ushort4*)x_bf)[i] = o;
        } else if (i < NX4 + NW4) {
            long long j = i - NX4;
            float4 v = ((const float4*)w_ih)[j];
            ushort4 o;
            o.x = f2bf(v.x); o.y = f2bf(v.y); o.z = f2bf(v.z); o.w = f2bf(v.w);
            ((ushort4*)wih_bf)[j] = o;
        } else if (i < NX4 + NW4 + NH16) {
            long long j = i - NX4 - NW4;
            ((uint4*)h0)[j] = make_uint4(0u, 0u, 0u, 0u);
        } else {
            long long j = i - NX4 - NW4 - NH16;
            ((uint4*)cnt)[j] = make_uint4(0u, 0u, 0u, 0u);
        }
    }
}

// ---------------------------------------------------------------- LSTM ----
// Persistent kernel. 256 blocks x 256 threads (1 block/CU via 132KB LDS).
// Block (r = bid&3, e4 = bid>>2): rows r*64..+64, gate cols {g*1024 + e4*16 + 0..15}.
// w_hh 64-col slice lives in LDS (bf16) for all 128 steps. c stays in registers.
//
// Sync: per-step, per-row-group barrier with NO fences. All h ping-pong
// traffic goes point-to-point through the device-coherent point:
//   producer: global_store_short sc0 sc1 -> s_waitcnt vmcnt(0) -> barrier
//             -> relaxed agent atomicAdd
//   consumer: relaxed agent spin -> __syncthreads -> relaxed agent 8B loads
// This removes the per-step buffer_wbl2 / L2-invalidate pair the
// release/acquire fences compiled to (round 1: WRITE_SIZE showed the whole
// 512KB h buffer written to HBM every step, h re-fetched from HBM every
// step, and the L2-resident w_ih working set evicted). x/w_ih/w_hh stay
// normally cached and now remain L2-hot across all 128 steps.
#define WHH_STRIDE 1032   // 1024 + 8 pad (shorts)

__global__ void __launch_bounds__(256, 1)
lstm_kernel(const unsigned short* __restrict__ x_bf,
            const unsigned short* __restrict__ wih_bf,
            const float* __restrict__ w_hh,
            const float* __restrict__ b_ih,
            const float* __restrict__ b_hh,
            unsigned short* __restrict__ h_buf,   // 2 * 256*1024 bf16 (ping-pong)
            float* __restrict__ h_f32,            // final h, fp32
            unsigned int* cnt)                    // [T][4] arrive counters, 128B apart
{
    extern __shared__ unsigned short lds_whh[];   // [64][WHH_STRIDE]
    const int tid  = threadIdx.x;
    const int bid  = blockIdx.x;
    const int r    = bid & 3;
    const int e4   = bid >> 2;
    const int wid  = tid >> 6;
    const int lane = tid & 63;
    const int quad = lane >> 4;
    const int ln   = lane & 15;

    // one-time: w_hh slice -> LDS bf16
    for (int idx4 = tid; idx4 < 64 * 1024 / 4; idx4 += 256) {
        int elem = idx4 * 4;
        int c = elem >> 10;          // local col 0..63
        int k = elem & 1023;
        int cg = (c >> 4) * E_ + e4 * 16 + (c & 15);   // gate*1024 + e
        float4 w = *(const float4*)(w_hh + (size_t)cg * E_ + k);
        unsigned int u0 = (unsigned int)f2bf(w.x) | ((unsigned int)f2bf(w.y) << 16);
        unsigned int u1 = (unsigned int)f2bf(w.z) | ((unsigned int)f2bf(w.w) << 16);
        *(uint2*)(lds_whh + (size_t)c * WHH_STRIDE + k) = make_uint2(u0, u1);
    }
    float bias4[4];
#pragma unroll
    for (int ct = 0; ct < 4; ++ct) {
        int cg = ct * E_ + e4 * 16 + ln;
        bias4[ct] = b_ih[cg] + b_hh[cg];
    }
    __syncthreads();

    const int rowA = r * 64 + wid * 16 + ln;   // A-operand row (batch index)
    const int colE = e4 * 16 + ln;             // e-column for C/D & cell state
    float c_reg[4] = {0.f, 0.f, 0.f, 0.f};

    for (int t = 0; t < T_; ++t) {
        const unsigned short* hsrc = h_buf + (size_t)(t & 1) * B_ * E_;
        unsigned short*       hdst = h_buf + (size_t)((t & 1) ^ 1) * B_ * E_;

        floatx4 acc[4];
#pragma unroll
        for (int ct = 0; ct < 4; ++ct)
            acc[ct] = (floatx4){bias4[ct], bias4[ct], bias4[ct], bias4[ct]};

        // ---- x phase: K = 512 (w_ih from hot L2). No h dependency:
        // runs BEFORE the barrier wait, overlapping other blocks' step t-1 tail.
        const unsigned short* xrow = x_bf + ((size_t)rowA * T_ + t) * I_ + quad * 8;
#pragma unroll 4
        for (int k0 = 0; k0 < I_; k0 += 32) {
            short8 a = *(const short8*)(xrow + k0);
#pragma unroll
            for (int ct = 0; ct < 4; ++ct) {
                int cgl = ct * E_ + e4 * 16 + ln;
                short8 b = *(const short8*)(wih_bf + (size_t)cgl * I_ + k0 + quad * 8);
                acc[ct] = __builtin_amdgcn_mfma_f32_16x16x32_bf16(a, b, acc[ct], 0, 0, 0);
            }
        }

        // ---- wait: all 64 blocks of row-group r published h_{t-1}. No fence:
        // h loads below bypass L1/L2 themselves.
        if (t) {
            if (tid == 0) {
                unsigned int* cp = cnt + ((size_t)(t - 1) * 4 + r) * 32;
                while (__hip_atomic_load(cp, __ATOMIC_RELAXED, __HIP_MEMORY_SCOPE_AGENT) < 64u)
                    __builtin_amdgcn_s_sleep(1);
            }
            __syncthreads();   // compiler barrier + all waves held until flag seen
        }

        // ---- h phase: K = 1024 (w_hh from LDS, h via coherent-point loads) ----
        const unsigned long long* hq =
            (const unsigned long long*)(hsrc + (size_t)rowA * E_) + quad * 2;
#pragma unroll 4
        for (int k0 = 0; k0 < E_; k0 += 32) {
            unsigned long long q0 = __hip_atomic_load(hq + (k0 >> 2),
                                                      __ATOMIC_RELAXED, __HIP_MEMORY_SCOPE_AGENT);
            unsigned long long q1 = __hip_atomic_load(hq + (k0 >> 2) + 1,
                                                      __ATOMIC_RELAXED, __HIP_MEMORY_SCOPE_AGENT);
            union { unsigned long long q[2]; short8 v; } u;
            u.q[0] = q0; u.q[1] = q1;
            short8 a = u.v;
#pragma unroll
            for (int ct = 0; ct < 4; ++ct) {
                short8 b = *(const short8*)(lds_whh + (size_t)(ct * 16 + ln) * WHH_STRIDE + k0 + quad * 8);
                acc[ct] = __builtin_amdgcn_mfma_f32_16x16x32_bf16(a, b, acc[ct], 0, 0, 0);
            }
        }
        // ---- elementwise cell update (gates i,f,g,o are lane-aligned) ----
#pragma unroll
        for (int i = 0; i < 4; ++i) {
            float ig = sigf(acc[0][i]);
            float fg = sigf(acc[1][i]);
            float gg = tanhf_(acc[2][i]);
            float og = sigf(acc[3][i]);
            float c = fg * c_reg[i] + ig * gg;
            c_reg[i] = c;
            float h = og * tanhf_(c);
            int row = r * 64 + wid * 16 + quad * 4 + i;   // C/D row = quad*4+reg
            store_short_coh(hdst + (size_t)row * E_ + colE, (unsigned int)f2bf(h));
            if (t == T_ - 1) h_f32[(size_t)row * E_ + colE] = h;
        }

        // ---- arrive: publish h_t for row-group r (no release fence) ----
        if (t != T_ - 1) {
            // drain this wave's coherent-point stores (asm stores are not in the
            // compiler's vmcnt model, so wait explicitly), then block barrier.
            asm volatile("s_waitcnt vmcnt(0)" ::: "memory");
            __syncthreads();
            if (tid == 0) {
                __hip_atomic_fetch_add(cnt + ((size_t)t * 4 + r) * 32, 1u,
                                       __ATOMIC_RELAXED, __HIP_MEMORY_SCOPE_AGENT);
            }
        }
        // t == T_-1: kernel end is an implicit device-scope release; h_f32 is
        // consumed by later kernels via stream ordering.
    }
}

// ------------------------------------------------------------- tf_gemm ----
// out[256,N] = [relu]( LN?(A)[256,K] @ W[N,K]^T + bias ) + LN?(res)
// tile 32x32, 4 waves of (mr,nc) 16x16 MFMA tiles. At most ONE of lnA/lnR used.
__global__ void __launch_bounds__(256)
tf_gemm(const float* __restrict__ A, int K,
        const float* __restrict__ lnA_g, const float* __restrict__ lnA_b,
        const float* __restrict__ W, const float* __restrict__ bias, int N,
        const float* __restrict__ res, const float* __restrict__ lnR_g, const float* __restrict__ lnR_b,
        float* __restrict__ out, int do_relu)
{
    __shared__ float s_mean[32], s_rstd[32];
    __shared__ float s_red[2][32][8];
    const int tid = threadIdx.x;
    const int bx = blockIdx.x;
    const int by = blockIdx.y;
    const int rowbase = by * 32;

    const float* stat_src = lnA_g ? A : (lnR_g ? res : nullptr);
    const int statK = lnA_g ? K : E_;
    if (stat_src) {
        int row_l = tid >> 3, seg = tid & 7;
        const float* rp = stat_src + (size_t)(rowbase + row_l) * statK;
        int chunk = statK >> 3;
        float s = 0.f, q = 0.f;
        for (int k = seg * chunk; k < seg * chunk + chunk; k += 4) {
            float4 v = *(const float4*)(rp + k);
            s += v.x + v.y + v.z + v.w;
            q += v.x * v.x + v.y * v.y + v.z * v.z + v.w * v.w;
        }
        s_red[0][row_l][seg] = s;
        s_red[1][row_l][seg] = q;
        __syncthreads();
        if (tid < 32) {
            float ss = 0.f, qq = 0.f;
#pragma unroll
            for (int j = 0; j < 8; ++j) { ss += s_red[0][tid][j]; qq += s_red[1][tid][j]; }
            float m = ss / statK;
            float var = qq / statK - m * m;
            s_mean[tid] = m;
            s_rstd[tid] = rsqrtf(var + EPS_);
        }
        __syncthreads();
    }

    const int wid = tid >> 6, lane = tid & 63, quad = lane >> 4, ln = lane & 15;
    const int mr = wid & 1, nc = wid >> 1;
    const int arow_l = mr * 16 + ln;
    const int col = bx * 32 + nc * 16 + ln;

    floatx4 acc = (floatx4){0.f, 0.f, 0.f, 0.f};
    const float* ap = A + (size_t)(rowbase + arow_l) * K;
    const float* wp = W + (size_t)col * K;
    const bool doLnA = (lnA_g != nullptr);
    float am = 0.f, ars = 1.f;
    if (doLnA) { am = s_mean[arow_l]; ars = s_rstd[arow_l]; }

#pragma unroll 4
    for (int k0 = 0; k0 < K; k0 += 32) {
        int kk = k0 + quad * 8;
        float4 a0 = *(const float4*)(ap + kk);
        float4 a1 = *(const float4*)(ap + kk + 4);
        short8 af, bf;
        if (doLnA) {
            float4 g0 = *(const float4*)(lnA_g + kk);
            float4 g1 = *(const float4*)(lnA_g + kk + 4);
            float4 h0 = *(const float4*)(lnA_b + kk);
            float4 h1 = *(const float4*)(lnA_b + kk + 4);
            af[0] = (short)f2bf((a0.x - am) * ars * g0.x + h0.x);
            af[1] = (short)f2bf((a0.y - am) * ars * g0.y + h0.y);
            af[2] = (short)f2bf((a0.z - am) * ars * g0.z + h0.z);
            af[3] = (short)f2bf((a0.w - am) * ars * g0.w + h0.w);
            af[4] = (short)f2bf((a1.x - am) * ars * g1.x + h1.x);
            af[5] = (short)f2bf((a1.y - am) * ars * g1.y + h1.y);
            af[6] = (short)f2bf((a1.z - am) * ars * g1.z + h1.z);
            af[7] = (short)f2bf((a1.w - am) * ars * g1.w + h1.w);
        } else {
            af[0] = (short)f2bf(a0.x); af[1] = (short)f2bf(a0.y);
            af[2] = (short)f2bf(a0.z); af[3] = (short)f2bf(a0.w);
            af[4] = (short)f2bf(a1.x); af[5] = (short)f2bf(a1.y);
            af[6] = (short)f2bf(a1.z); af[7] = (short)f2bf(a1.w);
        }
        float4 w0 = *(const float4*)(wp + kk);
        float4 w1 = *(const float4*)(wp + kk + 4);
        bf[0] = (short)f2bf(w0.x); bf[1] = (short)f2bf(w0.y);
        bf[2] = (short)f2bf(w0.z); bf[3] = (short)f2bf(w0.w);
        bf[4] = (short)f2bf(w1.x); bf[5] = (short)f2bf(w1.y);
        bf[6] = (short)f2bf(w1.z); bf[7] = (short)f2bf(w1.w);
        acc = __builtin_amdgcn_mfma_f32_16x16x32_bf16(af, bf, acc, 0, 0, 0);
    }

#pragma unroll
    for (int i = 0; i < 4; ++i) {
        int row_l = mr * 16 + quad * 4 + i;
        int row = rowbase + row_l;
        float v = acc[i] + bias[col];
        if (do_relu) v = fmaxf(v, 0.f);
        if (res) {
            float rv = res[(size_t)row * N + col];
            if (lnR_g) rv = (rv - s_mean[row_l]) * s_rstd[row_l] * lnR_g[col] + lnR_b[col];
            v += rv;
        }
        out[(size_t)row * N + col] = v;
    }
}

// ------------------------------------------------- double-LayerNorm ----
// out = LN_{g2,b2}( LN_{g1,b1}(in) ), per row of [256,1024]. 1 wave / row.
__global__ void __launch_bounds__(256)
dual_ln_kernel(const float* __restrict__ in,
               const float* __restrict__ g1, const float* __restrict__ b1,
               const float* __restrict__ g2, const float* __restrict__ b2,
               float* __restrict__ out)
{
    int wid = threadIdx.x >> 6, lane = threadIdx.x & 63;
    int row = blockIdx.x * 4 + wid;
    const float* rp = in + (size_t)row * E_;
    float x[16];
    float s = 0.f;
#pragma unroll
    for (int j = 0; j < 16; j += 4) {
        float4 v = *(const float4*)(rp + lane * 16 + j);
        x[j] = v.x; x[j + 1] = v.y; x[j + 2] = v.z; x[j + 3] = v.w;
        s += v.x + v.y + v.z + v.w;
    }
#pragma unroll
    for (int m = 32; m >= 1; m >>= 1) s += __shfl_xor(s, m, 64);
    float mean = s / E_;
    float q = 0.f;
#pragma unroll
    for (int j = 0; j < 16; ++j) { float d = x[j] - mean; q += d * d; }
#pragma unroll
    for (int m = 32; m >= 1; m >>= 1) q += __shfl_xor(q, m, 64);
    float rs = rsqrtf(q / E_ + EPS_);
    float s2 = 0.f;
#pragma unroll
    for (int j = 0; j < 16; ++j) {
        int k = lane * 16 + j;
        x[j] = (x[j] - mean) * rs * g1[k] + b1[k];
        s2 += x[j];
    }
#pragma unroll
    for (int m = 32; m >= 1; m >>= 1) s2 += __shfl_xor(s2, m, 64);
    float mean2 = s2 / E_;
    float q2 = 0.f;
#pragma unroll
    for (int j = 0; j < 16; ++j) { float d = x[j] - mean2; q2 += d * d; }
#pragma unroll
    for (int m = 32; m >= 1; m >>= 1) q2 += __shfl_xor(q2, m, 64);
    float rs2 = rsqrtf(q2 / E_ + EPS_);
#pragma unroll
    for (int j = 0; j < 16; ++j) {
        int k = lane * 16 + j;
        out[(size_t)row * E_ + k] = (x[j] - mean2) * rs2 * g2[k] + b2[k];
    }
}

// ----------------------------------------------------------- final head ----
// out[row, 0..21] = ( LN_{gn,bn}( LN_{g3,b3}(in[row]) ) ) @ fc_w^T + fc_b
__global__ void __launch_bounds__(64)
head_kernel(const float* __restrict__ in,
            const float* __restrict__ g1, const float* __restrict__ b1,
            const float* __restrict__ g2, const float* __restrict__ b2,
            const float* __restrict__ fc_w, const float* __restrict__ fc_b,
            float* __restrict__ out)
{
    int row = blockIdx.x;
    int lane = threadIdx.x;
    const float* rp = in + (size_t)row * E_;
    float x[16];
    float s = 0.f;
#pragma unroll
    for (int j = 0; j < 16; j += 4) {
        float4 v = *(const float4*)(rp + lane * 16 + j);
        x[j] = v.x; x[j + 1] = v.y; x[j + 2] = v.z; x[j + 3] = v.w;
        s += v.x + v.y + v.z + v.w;
    }
#pragma unroll
    for (int m = 32; m >= 1; m >>= 1) s += __shfl_xor(s, m, 64);
    float mean = s / E_;
    float q = 0.f;
#pragma unroll
    for (int j = 0; j < 16; ++j) { float d = x[j] - mean; q += d * d; }
#pragma unroll
    for (int m = 32; m >= 1; m >>= 1) q += __shfl_xor(q, m, 64);
    float rs = rsqrtf(q / E_ + EPS_);
    float s2 = 0.f;
#pragma unroll
    for (int j = 0; j < 16; ++j) {
        int k = lane * 16 + j;
        x[j] = (x[j] - mean) * rs * g1[k] + b1[k];
        s2 += x[j];
    }
#pragma unroll
    for (int m = 32; m >= 1; m >>= 1) s2 += __shfl_xor(s2, m, 64);
    float mean2 = s2 / E_;
    float q2 = 0.f;
#pragma unroll
    for (int j = 0; j < 16; ++j) { float d = x[j] - mean2; q2 += d * d; }
#pragma unroll
    for (int m = 32; m >= 1; m >>= 1) q2 += __shfl_xor(q2, m, 64);
    float rs2 = rsqrtf(q2 / E_ + EPS_);
#pragma unroll
    for (int j = 0; j < 16; ++j) {
        int k = lane * 16 + j;
        x[j] = (x[j] - mean2) * rs2 * g2[k] + b2[k];
    }
    for (int o = 0; o < O_; ++o) {
        const float* wp = fc_w + (size_t)o * E_ + lane * 16;
        float d = 0.f;
#pragma unroll
        for (int j = 0; j < 16; j += 4) {
            float4 v = *(const float4*)(wp + j);
            d += v.x * x[j] + v.y * x[j + 1] + v.z * x[j + 2] + v.w * x[j + 3];
        }
#pragma unroll
        for (int m = 32; m >= 1; m >>= 1) d += __shfl_xor(d, m, 64);
        if (lane == 0) out[(size_t)row * O_ + o] = d + fc_b[o];
    }
}

// ---------------------------------------------------------------- host ----
extern "C" void kernel_launch(void* const* d_in, const int* in_sizes, int n_in,
                              void* d_out, int out_size, void* d_ws, size_t ws_size,
                              hipStream_t stream) {
    (void)in_sizes; (void)n_in; (void)out_size; (void)ws_size;
    const float* x          = (const float*)d_in[0];
    const float* w_ih       = (const float*)d_in[1];
    const float* w_hh       = (const float*)d_in[2];
    const float* b_ih       = (const float*)d_in[3];
    const float* b_hh       = (const float*)d_in[4];
    const float* enc_attn_w = (const float*)d_in[5];
    const float* enc_attn_b = (const float*)d_in[6];
    const float* enc_out_w  = (const float*)d_in[7];
    const float* enc_out_b  = (const float*)d_in[8];
    const float* enc_ln1_g  = (const float*)d_in[9];
    const float* enc_ln1_b  = (const float*)d_in[10];
    const float* enc_ff1_w  = (const float*)d_in[11];
    const float* enc_ff1_b  = (const float*)d_in[12];
    const float* enc_ff2_w  = (const float*)d_in[13];
    const float* enc_ff2_b  = (const float*)d_in[14];
    const float* enc_ln2_g  = (const float*)d_in[15];
    const float* enc_ln2_b  = (const float*)d_in[16];
    const float* enc_norm_g = (const float*)d_in[17];
    const float* enc_norm_b = (const float*)d_in[18];
    const float* dec_sa_w   = (const float*)d_in[19];
    const float* dec_sa_b   = (const float*)d_in[20];
    const float* dec_sa_out_w = (const float*)d_in[21];
    const float* dec_sa_out_b = (const float*)d_in[22];
    const float* dec_ln1_g  = (const float*)d_in[23];
    const float* dec_ln1_b  = (const float*)d_in[24];
    const float* dec_ca_w   = (const float*)d_in[25];
    const float* dec_ca_b   = (const float*)d_in[26];
    const float* dec_ca_out_w = (const float*)d_in[27];
    const float* dec_ca_out_b = (const float*)d_in[28];
    const float* dec_ln2_g  = (const float*)d_in[29];
    const float* dec_ln2_b  = (const float*)d_in[30];
    const float* dec_ff1_w  = (const float*)d_in[31];
    const float* dec_ff1_b  = (const float*)d_in[32];
    const float* dec_ff2_w  = (const float*)d_in[33];
    const float* dec_ff2_b  = (const float*)d_in[34];
    const float* dec_ln3_g  = (const float*)d_in[35];
    const float* dec_ln3_b  = (const float*)d_in[36];
    const float* dec_norm_g = (const float*)d_in[37];
    const float* dec_norm_b = (const float*)d_in[38];
    const float* fc_w       = (const float*)d_in[39];
    const float* fc_b       = (const float*)d_in[40];
    float* outp = (float*)d_out;

    // ---- workspace layout (~45 MB) ----
    char* wsp = (char*)d_ws;
    unsigned short* x_bf   = (unsigned short*)wsp; wsp += (size_t)B_ * T_ * I_ * 2;
    unsigned short* wih_bf = (unsigned short*)wsp; wsp += (size_t)4 * E_ * I_ * 2;
    unsigned short* h_buf  = (unsigned short*)wsp; wsp += (size_t)2 * B_ * E_ * 2;
    float* h_f32 = (float*)wsp; wsp += (size_t)B_ * E_ * 4;
    float* v_buf = (float*)wsp; wsp += (size_t)B_ * E_ * 4;
    float* uA    = (float*)wsp; wsp += (size_t)B_ * E_ * 4;
    float* uB    = (float*)wsp; wsp += (size_t)B_ * E_ * 4;
    float* t3    = (float*)wsp; wsp += (size_t)B_ * E_ * 4;
    float* memb  = (float*)wsp; wsp += (size_t)B_ * E_ * 4;
    float* F_buf = (float*)wsp; wsp += (size_t)B_ * F_ * 4;
    unsigned int* cnt = (unsigned int*)wsp; wsp += (size_t)T_ * 4 * 32 * 4;  // 64 KB barrier counters

    // ---- phase 1: prep ----
    hipLaunchKernelGGL(prep_kernel, dim3(1024), dim3(256), 0, stream,
                       x, w_ih, x_bf, wih_bf, h_buf, cnt);

    // ---- phase 2: LSTM scan (cooperative launch for co-residency;
    //               sync is the fence-free per-row-group barrier) ----
    {
        void* args[] = {(void*)&x_bf, (void*)&wih_bf, (void*)&w_hh, (void*)&b_ih,
                        (void*)&b_hh, (void*)&h_buf, (void*)&h_f32, (void*)&cnt};
        hipLaunchCooperativeKernel((void*)lstm_kernel, dim3(256), dim3(256),
                                   args, 64 * WHH_STRIDE * 2, stream);
    }

    // ---- phase 3: transformer ----
    auto gemm = [&](const float* A, int K, const float* g, const float* bA,
                    const float* Wp, const float* bias, int N,
                    const float* res, const float* gR, const float* bR,
                    float* out, int relu_) {
        hipLaunchKernelGGL(tf_gemm, dim3(N / 32, 8), dim3(256), 0, stream,
                           A, K, g, bA, Wp, bias, N, res, gR, bR, out, relu_);
    };
    const float* FN = nullptr;

    // encoder: state (cur, pending LN cg_/cb_)
    const float* cur = h_f32; const float* cg_ = nullptr; const float* cb_ = nullptr;
    for (int l = 0; l < L_; ++l) {
        const float* wv = enc_attn_w + ((size_t)l * 3 * E_ + 2 * E_) * E_;
        const float* bv = enc_attn_b + (size_t)l * 3 * E_ + 2 * E_;
        gemm(cur, E_, cg_, cb_, wv, bv, E_, FN, FN, FN, v_buf, 0);
        gemm(v_buf, E_, FN, FN, enc_out_w + (size_t)l * E_ * E_, enc_out_b + (size_t)l * E_, E_,
             cur, cg_, cb_, uA, 0);
        gemm(uA, E_, enc_ln1_g + l * E_, enc_ln1_b + l * E_,
             enc_ff1_w + (size_t)l * F_ * E_, enc_ff1_b + (size_t)l * F_, F_,
             FN, FN, FN, F_buf, 1);
        gemm(F_buf, F_, FN, FN, enc_ff2_w + (size_t)l * E_ * F_, enc_ff2_b + (size_t)l * E_, E_,
             uA, enc_ln1_g + l * E_, enc_ln1_b + l * E_, uB, 0);
        cur = uB; cg_ = enc_ln2_g + l * E_; cb_ = enc_ln2_b + l * E_;
    }
    hipLaunchKernelGGL(dual_ln_kernel, dim3(64), dim3(256), 0, stream,
                       uB, cg_, cb_, enc_norm_g, enc_norm_b, memb);

    // decoder
    cur = h_f32; cg_ = nullptr; cb_ = nullptr;
    for (int l = 0; l < L_; ++l) {
        const float* wv = dec_sa_w + ((size_t)l * 3 * E_ + 2 * E_) * E_;
        const float* bv = dec_sa_b + (size_t)l * 3 * E_ + 2 * E_;
        gemm(cur, E_, cg_, cb_, wv, bv, E_, FN, FN, FN, v_buf, 0);
        gemm(v_buf, E_, FN, FN, dec_sa_out_w + (size_t)l * E_ * E_, dec_sa_out_b + (size_t)l * E_, E_,
             cur, cg_, cb_, uA, 0);                              // t1 = uA (pending ln1)
        const float* wv2 = dec_ca_w + ((size_t)l * 3 * E_ + 2 * E_) * E_;
        const float* bv2 = dec_ca_b + (size_t)l * 3 * E_ + 2 * E_;
        gemm(memb, E_, FN, FN, wv2, bv2, E_, FN, FN, FN, v_buf, 0);
        gemm(v_buf, E_, FN, FN, dec_ca_out_w + (size_t)l * E_ * E_, dec_ca_out_b + (size_t)l * E_, E_,
             uA, dec_ln1_g + l * E_, dec_ln1_b + l * E_, uB, 0); // t2 = uB (pending ln2)
        gemm(uB, E_, dec_ln2_g + l * E_, dec_ln2_b + l * E_,
             dec_ff1_w + (size_t)l * F_ * E_, dec_ff1_b + (size_t)l * F_, F_,
             FN, FN, FN, F_buf, 1);
        gemm(F_buf, F_, FN, FN, dec_ff2_w + (size_t)l * E_ * F_, dec_ff2_b + (size_t)l * E_, E_,
             uB, dec_ln2_g + l * E_, dec_ln2_b + l * E_, t3, 0); // t3 (pending ln3)
        cur = t3; cg_ = dec_ln3_g + l * E_; cb_ = dec_ln3_b + l * E_;
    }
    hipLaunchKernelGGL(head_kernel, dim3(256), dim3(64), 0, stream,
                       t3, cg_, cb_, dec_norm_g, dec_norm_b, fc_w, fc_b, outp);
}